// Round 5
// baseline (298.724 us; speedup 1.0000x reference)
//
#include <hip/hip_runtime.h>
#include <math.h>

#define NVERT 6890
#define NJN   24
#define NBETA 10
#define NPOSE 207
#define NBATCH 512

// ws layout (floats):
//  [0)               pdT : NVERT*624   (posedirs repacked [v][3][208], zero-padded)
//  [4299360)         jb  : 72 (Jbase) + 720 (JB)  = 792
//  [4300152)         lrot: 512*207 = 105984
//  [4406136)         g3  : 512*288 = 147456
//  total 4553592 floats = 18.2 MB

__device__ const int c_parent[23] = {0,0,0,1,2,3,4,5,6,7,8,9,9,9,12,13,14,16,17,18,19,20,21};

// ---------- kernel 0: repack posedirs into aligned padded layout ----------
__global__ void k_tpose(const float* __restrict__ pd, float* __restrict__ pdT) {
    const int total = NVERT * 624;
    for (int idx = blockIdx.x * blockDim.x + threadIdx.x; idx < total;
         idx += gridDim.x * blockDim.x) {
        int v = idx / 624;
        int r = idx - v * 624;
        int d = r / 208;
        int p = r - d * 208;
        pdT[idx] = (p < NPOSE) ? pd[v * 621 + d * NPOSE + p] : 0.0f;
    }
}

// ---------- kernel 1: fold J_regressor through template+shapedirs ----------
// jb[0..71]  = Jbase[j*3+d] = sum_v Jr[j,v] * vt[v,d]
// jb[72 + (j*3+d)*10 + k] = sum_v Jr[j,v] * shapedirs[v,d,k]
__global__ void k_jreg(const float* __restrict__ Jr, const float* __restrict__ vt,
                       const float* __restrict__ sh, float* __restrict__ jb) {
    const int jd = blockIdx.x;         // 0..71
    const int j = jd / 3, d = jd % 3;
    float acc[11];
#pragma unroll
    for (int k = 0; k < 11; k++) acc[k] = 0.0f;
    for (int v = threadIdx.x; v < NVERT; v += 256) {
        float r = Jr[j * NVERT + v];
        acc[0] += r * vt[v * 3 + d];
        const float* sp = sh + v * 30 + d * 10;
#pragma unroll
        for (int k = 0; k < 10; k++) acc[1 + k] += r * sp[k];
    }
#pragma unroll
    for (int k = 0; k < 11; k++) {
#pragma unroll
        for (int off = 32; off > 0; off >>= 1)
            acc[k] += __shfl_down(acc[k], off);
    }
    __shared__ float red[4][11];
    const int lane = threadIdx.x & 63, wid = threadIdx.x >> 6;
    if (lane == 0) {
#pragma unroll
        for (int k = 0; k < 11; k++) red[wid][k] = acc[k];
    }
    __syncthreads();
    if (threadIdx.x == 0) {
#pragma unroll
        for (int k = 0; k < 11; k++) {
            float s = red[0][k] + red[1][k] + red[2][k] + red[3][k];
            if (k == 0) jb[jd] = s;
            else jb[72 + jd * 10 + (k - 1)] = s;
        }
    }
}

// ---------- kernel 2: per-batch rodrigues + chain + final 3x4 transforms ----------
// NOTE: MUST run with blockDim >= 72 (the J computation uses 72 threads).
__global__ void k_pose(const float* __restrict__ pose, const float* __restrict__ beta,
                       const float* __restrict__ jb, float* __restrict__ lrot,
                       float* __restrict__ g3) {
    const int b = blockIdx.x, t = threadIdx.x;
    __shared__ float sR[24][9], sJ[24][3], sGl[24][12], sG[24][12];
    if (t < 24) {
        const float* th = pose + b * 72 + t * 3;
        float tx = th[0], ty = th[1], tz = th[2];
        float ax = tx + 1e-8f, ay = ty + 1e-8f, az = tz + 1e-8f;
        float ang = sqrtf(ax * ax + ay * ay + az * az);
        float inv = 1.0f / ang;
        float nx = tx * inv, ny = ty * inv, nz = tz * inv;
        float sw, cw;
        sincosf(0.5f * ang, &sw, &cw);
        float qw = cw, qx = sw * nx, qy = sw * ny, qz = sw * nz;
        float qn = 1.0f / sqrtf(qw * qw + qx * qx + qy * qy + qz * qz);
        qw *= qn; qx *= qn; qy *= qn; qz *= qn;
        float w2 = qw * qw, x2 = qx * qx, y2 = qy * qy, z2 = qz * qz;
        float wx = qw * qx, wy = qw * qy, wz = qw * qz;
        float xy = qx * qy, xz = qx * qz, yz = qy * qz;
        float R[9];
        R[0] = w2 + x2 - y2 - z2; R[1] = 2.f * (xy - wz); R[2] = 2.f * (wy + xz);
        R[3] = 2.f * (wz + xy);   R[4] = w2 - x2 + y2 - z2; R[5] = 2.f * (yz - wx);
        R[6] = 2.f * (xz - wy);   R[7] = 2.f * (wx + yz);   R[8] = w2 - x2 - y2 + z2;
#pragma unroll
        for (int k = 0; k < 9; k++) sR[t][k] = R[k];
        if (t >= 1) {
            float* lp = lrot + b * NPOSE + (t - 1) * 9;
#pragma unroll
            for (int k = 0; k < 9; k++)
                lp[k] = R[k] - ((k == 0 || k == 4 || k == 8) ? 1.f : 0.f);
        }
    }
    if (t < 72) {
        const int j = t / 3;
        float Jv = jb[t];
        const float* c = jb + 72 + t * 10;
        const float* be = beta + b * NBETA;
#pragma unroll
        for (int k = 0; k < 10; k++) Jv += c[k] * be[k];
        sJ[j][t - j * 3] = Jv;
    }
    __syncthreads();
    if (t < 24) {
#pragma unroll
        for (int r = 0; r < 3; r++) {
            sGl[t][r * 4 + 0] = sR[t][r * 3 + 0];
            sGl[t][r * 4 + 1] = sR[t][r * 3 + 1];
            sGl[t][r * 4 + 2] = sR[t][r * 3 + 2];
            float jr = sJ[t][r];
            if (t > 0) jr -= sJ[c_parent[t - 1]][r];
            sGl[t][r * 4 + 3] = jr;
        }
    }
    __syncthreads();
    if (t < 12) sG[0][t] = sGl[0][t];
    __syncthreads();
    for (int i = 1; i < 24; i++) {
        if (t < 12) {
            const int m = t >> 2, n = t & 3;
            const int p = c_parent[i - 1];
            float val = sG[p][m * 4 + 0] * sGl[i][0 + n]
                      + sG[p][m * 4 + 1] * sGl[i][4 + n]
                      + sG[p][m * 4 + 2] * sGl[i][8 + n];
            if (n == 3) val += sG[p][m * 4 + 3];
            sG[i][t] = val;
        }
        __syncthreads();
    }
    if (t < 24) {
        float jx = sJ[t][0], jy = sJ[t][1], jz = sJ[t][2];
        float* gp = g3 + b * 288 + t * 12;
#pragma unroll
        for (int m = 0; m < 3; m++) {
            float g0 = sG[t][m * 4 + 0], g1 = sG[t][m * 4 + 1];
            float g2 = sG[t][m * 4 + 2], g3v = sG[t][m * 4 + 3];
            float tc = g0 * jx + g1 * jy + g2 * jz;
            gp[m * 4 + 0] = g0; gp[m * 4 + 1] = g1;
            gp[m * 4 + 2] = g2; gp[m * 4 + 3] = g3v - tc;
        }
    }
}

// ---------- kernel 3: fused vertex kernel ----------
// block 256 thr; tile = 16 batches x 128 vertices; per-thread 2b x 4v x 3d regs.
// LDS strides: lrot 212, g3 292, beta 11 (bank-aware, 16B-aligned where b128-read)
__global__ void k_main(const float* __restrict__ beta, const float* __restrict__ vt,
                       const float* __restrict__ sh, const float* __restrict__ wts,
                       const float* __restrict__ pdT, const float* __restrict__ lrot,
                       const float* __restrict__ g3, float* __restrict__ out) {
    __shared__ float sLrot[16 * 212];
    __shared__ float sG3[16 * 292];
    __shared__ float sBeta[16 * 11];
    const int b0 = blockIdx.x * 16;
    const int v0 = blockIdx.y * 128;
    const int tid = threadIdx.x;

    for (int idx = tid; idx < 16 * 208; idx += 256) {
        int bb = idx / 208, p = idx - bb * 208;
        sLrot[bb * 212 + p] = (p < NPOSE) ? lrot[(b0 + bb) * NPOSE + p] : 0.0f;
    }
    for (int idx = tid; idx < 16 * 288; idx += 256) {
        int bb = idx / 288, c = idx - bb * 288;
        sG3[bb * 292 + c] = g3[(b0 + bb) * 288 + c];
    }
    if (tid < 160) {
        int bb = tid / 10, k = tid - bb * 10;
        sBeta[bb * 11 + k] = beta[(b0 + bb) * NBETA + k];
    }
    __syncthreads();

    const int bg = tid & 7;     // 8 groups x 2 batches
    const int vg = tid >> 3;    // 0..31
    int vs[4]; bool vok[4];
#pragma unroll
    for (int s = 0; s < 4; s++) {
        int v = v0 + vg + 32 * s;
        vok[s] = (v < NVERT);
        vs[s] = vok[s] ? v : (NVERT - 1);
    }

    // init accumulators = v_template + shapedirs . beta
    float a[2][4][3];
#pragma unroll
    for (int s = 0; s < 4; s++) {
        const float* vtp = vt + vs[s] * 3;
        float t0 = vtp[0], t1 = vtp[1], t2 = vtp[2];
        const float* shp = sh + vs[s] * 30;
#pragma unroll
        for (int i = 0; i < 2; i++) {
            const float* bp = &sBeta[(bg * 2 + i) * 11];
            float x = t0, y = t1, z = t2;
#pragma unroll
            for (int k = 0; k < 10; k++) {
                float bk = bp[k];
                x += shp[k] * bk; y += shp[10 + k] * bk; z += shp[20 + k] * bk;
            }
            a[i][s][0] = x; a[i][s][1] = y; a[i][s][2] = z;
        }
    }

    // pose-blend: a += posedirs . lrotmin   (K=208 padded, float4 streams)
    const float4* lrp0 = (const float4*)&sLrot[(bg * 2 + 0) * 212];
    const float4* lrp1 = (const float4*)&sLrot[(bg * 2 + 1) * 212];
    const float* pds[4];
#pragma unroll
    for (int s = 0; s < 4; s++) pds[s] = pdT + (size_t)vs[s] * 624;

    for (int p4 = 0; p4 < 52; p4++) {
        float4 l0 = lrp0[p4];
        float4 l1 = lrp1[p4];
#pragma unroll
        for (int s = 0; s < 4; s++) {
            const float* pv = pds[s] + p4 * 4;
            float4 q0 = *(const float4*)(pv);
            float4 q1 = *(const float4*)(pv + 208);
            float4 q2 = *(const float4*)(pv + 416);
            a[0][s][0] += q0.x * l0.x + q0.y * l0.y + q0.z * l0.z + q0.w * l0.w;
            a[0][s][1] += q1.x * l0.x + q1.y * l0.y + q1.z * l0.z + q1.w * l0.w;
            a[0][s][2] += q2.x * l0.x + q2.y * l0.y + q2.z * l0.z + q2.w * l0.w;
            a[1][s][0] += q0.x * l1.x + q0.y * l1.y + q0.z * l1.z + q0.w * l1.w;
            a[1][s][1] += q1.x * l1.x + q1.y * l1.y + q1.z * l1.z + q1.w * l1.w;
            a[1][s][2] += q2.x * l1.x + q2.y * l1.y + q2.z * l1.z + q2.w * l1.w;
        }
    }

    // LBS blend: T = sum_j w[v,j] * G3[b,j], then out = T . [a,1]
#pragma unroll
    for (int i = 0; i < 2; i++) {
        const int bl = bg * 2 + i;
        const float* gb = &sG3[bl * 292];
        float T[4][12];
#pragma unroll
        for (int s = 0; s < 4; s++)
#pragma unroll
            for (int c = 0; c < 12; c++) T[s][c] = 0.0f;
        for (int j = 0; j < 24; j++) {
            float4 g0 = *(const float4*)(gb + j * 12);
            float4 g1 = *(const float4*)(gb + j * 12 + 4);
            float4 g2 = *(const float4*)(gb + j * 12 + 8);
#pragma unroll
            for (int s = 0; s < 4; s++) {
                float wv = wts[vs[s] * NJN + j];
                T[s][0] += wv * g0.x; T[s][1] += wv * g0.y;
                T[s][2] += wv * g0.z; T[s][3] += wv * g0.w;
                T[s][4] += wv * g1.x; T[s][5] += wv * g1.y;
                T[s][6] += wv * g1.z; T[s][7] += wv * g1.w;
                T[s][8] += wv * g2.x; T[s][9] += wv * g2.y;
                T[s][10] += wv * g2.z; T[s][11] += wv * g2.w;
            }
        }
#pragma unroll
        for (int s = 0; s < 4; s++) {
            float x = a[i][s][0], y = a[i][s][1], z = a[i][s][2];
            float o0 = T[s][0] * x + T[s][1] * y + T[s][2] * z + T[s][3];
            float o1 = T[s][4] * x + T[s][5] * y + T[s][6] * z + T[s][7];
            float o2 = T[s][8] * x + T[s][9] * y + T[s][10] * z + T[s][11];
            if (vok[s]) {
                float* op = out + ((size_t)(b0 + bl) * NVERT + (v0 + vg + 32 * s)) * 3;
                op[0] = o0; op[1] = o1; op[2] = o2;
            }
        }
    }
}

extern "C" void kernel_launch(void* const* d_in, const int* in_sizes, int n_in,
                              void* d_out, int out_size, void* d_ws, size_t ws_size,
                              hipStream_t stream) {
    const float* pose = (const float*)d_in[0];
    const float* beta = (const float*)d_in[1];
    const float* vtm  = (const float*)d_in[2];
    const float* sh   = (const float*)d_in[3];
    const float* pd   = (const float*)d_in[4];
    const float* Jr   = (const float*)d_in[5];
    const float* wts  = (const float*)d_in[6];
    float* out = (float*)d_out;

    float* w    = (float*)d_ws;
    float* pdT  = w;                      // 4299360
    float* jb   = w + 4299360;            // 792
    float* lrot = jb + 792;               // 105984
    float* g3   = lrot + NBATCH * NPOSE;  // 147456

    k_tpose<<<4096, 256, 0, stream>>>(pd, pdT);
    k_jreg<<<72, 256, 0, stream>>>(Jr, vtm, sh, jb);
    k_pose<<<NBATCH, 128, 0, stream>>>(pose, beta, jb, lrot, g3);
    k_main<<<dim3(32, 54), 256, 0, stream>>>(beta, vtm, sh, wts, pdT, lrot, g3, out);
}

// Round 9
// 199.195 us; speedup vs baseline: 1.4997x; 1.4997x over previous
//
#include <hip/hip_runtime.h>
#include <hip/hip_bf16.h>
#include <math.h>

#define NVERT 6890
#define NJN   24
#define NBETA 10
#define NPOSE 207
#define NBATCH 512
#define KDIM  224          // 207 lrotmin + 10 beta + 7 zero pad
#define NCOL  20670        // NVERT*3
#define NPAD  20736        // 81*256 (GEMM N padding)

typedef __attribute__((ext_vector_type(8))) short bh8;   // 8 bf16 in 4 VGPRs
typedef __attribute__((ext_vector_type(4))) float f4;

__device__ const int c_parent[23] = {0,0,0,1,2,3,4,5,6,7,8,9,9,9,12,13,14,16,17,18,19,20,21};

// ws layout:
//  Bt  : bf16 [NPAD][KDIM]          = 4,644,864 bf16  (9,289,728 B)
//  A   : bf16 [NBATCH][KDIM]        =   114,688 bf16  (  229,376 B)
//  g3  : f32  [NBATCH][24][12]      =   147,456 f
//  jb  : f32  72 + 720              =       792 f
//  wT  : f32  [24][6912]            =   165,888 f
//  total ~10.8 MB

// ---------- kernel 0: repack B^T (bf16, k-contiguous) + weights transpose ----------
__global__ void k_prep(const float* __restrict__ pd, const float* __restrict__ sh,
                       const float* __restrict__ wts,
                       __hip_bfloat16* __restrict__ Bt, float* __restrict__ wT) {
    const int btTotal = NPAD * KDIM;          // 4,644,864
    const int wtTotal = NJN * NVERT;          // 165,360
    const int total = btTotal + wtTotal;
    for (int idx = blockIdx.x * blockDim.x + threadIdx.x; idx < total;
         idx += gridDim.x * blockDim.x) {
        if (idx < btTotal) {
            int col = idx / KDIM;
            int k = idx - col * KDIM;
            float val = 0.0f;
            if (col < NCOL) {
                int v = col / 3, d = col - v * 3;
                if (k < NPOSE)      val = pd[v * 621 + d * 207 + k];
                else if (k < 217)   val = sh[v * 30 + d * 10 + (k - 207)];
            }
            Bt[idx] = __float2bfloat16(val);
        } else {
            int r = idx - btTotal;
            int j = r / NVERT, v = r - j * NVERT;
            wT[j * 6912 + v] = wts[v * NJN + j];
        }
    }
}

// ---------- kernel 1: fold J_regressor through template+shapedirs ----------
__global__ void k_jreg(const float* __restrict__ Jr, const float* __restrict__ vt,
                       const float* __restrict__ sh, float* __restrict__ jb) {
    const int jd = blockIdx.x;         // 0..71
    const int j = jd / 3, d = jd % 3;
    float acc[11];
#pragma unroll
    for (int k = 0; k < 11; k++) acc[k] = 0.0f;
    for (int v = threadIdx.x; v < NVERT; v += 256) {
        float r = Jr[j * NVERT + v];
        acc[0] += r * vt[v * 3 + d];
        const float* sp = sh + v * 30 + d * 10;
#pragma unroll
        for (int k = 0; k < 10; k++) acc[1 + k] += r * sp[k];
    }
#pragma unroll
    for (int k = 0; k < 11; k++) {
#pragma unroll
        for (int off = 32; off > 0; off >>= 1)
            acc[k] += __shfl_down(acc[k], off);
    }
    __shared__ float red[4][11];
    const int lane = threadIdx.x & 63, wid = threadIdx.x >> 6;
    if (lane == 0) {
#pragma unroll
        for (int k = 0; k < 11; k++) red[wid][k] = acc[k];
    }
    __syncthreads();
    if (threadIdx.x == 0) {
#pragma unroll
        for (int k = 0; k < 11; k++) {
            float s = red[0][k] + red[1][k] + red[2][k] + red[3][k];
            if (k == 0) jb[jd] = s;
            else jb[72 + jd * 10 + (k - 1)] = s;
        }
    }
}

// ---------- kernel 2: rodrigues + chain -> A row (bf16) + final 3x4 transforms ----------
// blockDim must be >= 72.
__global__ void k_pose(const float* __restrict__ pose, const float* __restrict__ beta,
                       const float* __restrict__ jb, __hip_bfloat16* __restrict__ A,
                       float* __restrict__ g3) {
    const int b = blockIdx.x, t = threadIdx.x;
    __shared__ float sR[24][9], sJ[24][3], sGl[24][12], sG[24][12];
    if (t < 24) {
        const float* th = pose + b * 72 + t * 3;
        float tx = th[0], ty = th[1], tz = th[2];
        float ax = tx + 1e-8f, ay = ty + 1e-8f, az = tz + 1e-8f;
        float ang = sqrtf(ax * ax + ay * ay + az * az);
        float inv = 1.0f / ang;
        float nx = tx * inv, ny = ty * inv, nz = tz * inv;
        float sw, cw;
        sincosf(0.5f * ang, &sw, &cw);
        float qw = cw, qx = sw * nx, qy = sw * ny, qz = sw * nz;
        float qn = 1.0f / sqrtf(qw * qw + qx * qx + qy * qy + qz * qz);
        qw *= qn; qx *= qn; qy *= qn; qz *= qn;
        float w2 = qw * qw, x2 = qx * qx, y2 = qy * qy, z2 = qz * qz;
        float wx = qw * qx, wy = qw * qy, wz = qw * qz;
        float xy = qx * qy, xz = qx * qz, yz = qy * qz;
        float R[9];
        R[0] = w2 + x2 - y2 - z2; R[1] = 2.f * (xy - wz); R[2] = 2.f * (wy + xz);
        R[3] = 2.f * (wz + xy);   R[4] = w2 - x2 + y2 - z2; R[5] = 2.f * (yz - wx);
        R[6] = 2.f * (xz - wy);   R[7] = 2.f * (wx + yz);   R[8] = w2 - x2 - y2 + z2;
#pragma unroll
        for (int k = 0; k < 9; k++) sR[t][k] = R[k];
        if (t >= 1) {
            __hip_bfloat16* ap = A + b * KDIM + (t - 1) * 9;
#pragma unroll
            for (int k = 0; k < 9; k++)
                ap[k] = __float2bfloat16(R[k] - ((k == 0 || k == 4 || k == 8) ? 1.f : 0.f));
        }
    }
    if (t < NBETA) A[b * KDIM + 207 + t] = __float2bfloat16(beta[b * NBETA + t]);
    if (t < 7)     A[b * KDIM + 217 + t] = __float2bfloat16(0.0f);
    if (t < 72) {
        const int j = t / 3;
        float Jv = jb[t];
        const float* c = jb + 72 + t * 10;
        const float* be = beta + b * NBETA;
#pragma unroll
        for (int k = 0; k < 10; k++) Jv += c[k] * be[k];
        sJ[j][t - j * 3] = Jv;
    }
    __syncthreads();
    if (t < 24) {
#pragma unroll
        for (int r = 0; r < 3; r++) {
            sGl[t][r * 4 + 0] = sR[t][r * 3 + 0];
            sGl[t][r * 4 + 1] = sR[t][r * 3 + 1];
            sGl[t][r * 4 + 2] = sR[t][r * 3 + 2];
            float jr = sJ[t][r];
            if (t > 0) jr -= sJ[c_parent[t - 1]][r];
            sGl[t][r * 4 + 3] = jr;
        }
    }
    __syncthreads();
    if (t < 12) sG[0][t] = sGl[0][t];
    __syncthreads();
    for (int i = 1; i < 24; i++) {
        if (t < 12) {
            const int m = t >> 2, n = t & 3;
            const int p = c_parent[i - 1];
            float val = sG[p][m * 4 + 0] * sGl[i][0 + n]
                      + sG[p][m * 4 + 1] * sGl[i][4 + n]
                      + sG[p][m * 4 + 2] * sGl[i][8 + n];
            if (n == 3) val += sG[p][m * 4 + 3];
            sG[i][t] = val;
        }
        __syncthreads();
    }
    if (t < 24) {
        float jx = sJ[t][0], jy = sJ[t][1], jz = sJ[t][2];
        float* gp = g3 + b * 288 + t * 12;
#pragma unroll
        for (int m = 0; m < 3; m++) {
            float g0 = sG[t][m * 4 + 0], g1 = sG[t][m * 4 + 1];
            float g2 = sG[t][m * 4 + 2], g3v = sG[t][m * 4 + 3];
            float tc = g0 * jx + g1 * jy + g2 * jz;
            gp[m * 4 + 0] = g0; gp[m * 4 + 1] = g1;
            gp[m * 4 + 2] = g2; gp[m * 4 + 3] = g3v - tc;
        }
    }
}

// ---------- kernel 3: MFMA GEMM  v_posed = A[512,224] x B[224,20670] + v_template ----------
// 16x16x32 bf16 MFMA. Wave: 2 m-tiles x 4 n-frags (32x64 C). Block: 4 waves (32x256).
// A-frag: row = lane&15, k = kk*32 + (lane>>4)*8 + e   (k-perm cancels A vs B)
// C/D  : col = lane&15, row = (lane>>4)*4 + r          [m89-verified]
__global__ __launch_bounds__(256) void k_gemm(const __hip_bfloat16* __restrict__ A,
                                              const __hip_bfloat16* __restrict__ Bt,
                                              const float* __restrict__ vt,
                                              float* __restrict__ out) {
    const int lane = threadIdx.x & 63;
    const int wv = threadIdx.x >> 6;
    const int m0 = blockIdx.y * 32;
    const int n0 = blockIdx.x * 256 + wv * 64;
    const int l15 = lane & 15, lg = lane >> 4;

    const short* Ap = (const short*)A + (m0 + l15) * KDIM + lg * 8;
    const short* Bp = (const short*)Bt + (size_t)(n0 + l15) * KDIM + lg * 8;

    f4 acc[2][4];
#pragma unroll
    for (int mt = 0; mt < 2; mt++)
#pragma unroll
        for (int nr = 0; nr < 4; nr++) acc[mt][nr] = (f4){0.f, 0.f, 0.f, 0.f};

#pragma unroll
    for (int kk = 0; kk < 7; kk++) {
        bh8 a0 = *(const bh8*)(Ap + kk * 32);
        bh8 a1 = *(const bh8*)(Ap + 16 * KDIM + kk * 32);
#pragma unroll
        for (int nr = 0; nr < 4; nr++) {
            bh8 b = *(const bh8*)(Bp + (size_t)nr * 16 * KDIM + kk * 32);
            acc[0][nr] = __builtin_amdgcn_mfma_f32_16x16x32_bf16(a0, b, acc[0][nr], 0, 0, 0);
            acc[1][nr] = __builtin_amdgcn_mfma_f32_16x16x32_bf16(a1, b, acc[1][nr], 0, 0, 0);
        }
    }

#pragma unroll
    for (int mt = 0; mt < 2; mt++) {
#pragma unroll
        for (int nr = 0; nr < 4; nr++) {
            int col = n0 + nr * 16 + l15;
            if (col < NCOL) {
                float tv = vt[col];
                int rowb = m0 + mt * 16 + lg * 4;
#pragma unroll
                for (int r = 0; r < 4; r++)
                    out[(size_t)(rowb + r) * NCOL + col] = acc[mt][nr][r] + tv;
            }
        }
    }
}

// ---------- kernel 4: LBS blend, in-place on d_out ----------
// block 256; tile 16 batches x 128 verts; per-thread 2b x 4v. G3 in LDS; w from wT (coalesced).
__global__ __launch_bounds__(256) void k_lbs(const float* __restrict__ g3,
                                             const float* __restrict__ wT,
                                             float* __restrict__ out) {
    __shared__ float sG3[16 * 292];
    const int b0 = blockIdx.x * 16;
    const int v0 = blockIdx.y * 128;
    const int tid = threadIdx.x;
    for (int idx = tid; idx < 16 * 288; idx += 256) {
        int bb = idx / 288, c = idx - bb * 288;
        sG3[bb * 292 + c] = g3[(b0 + bb) * 288 + c];
    }
    __syncthreads();

    const int bg = tid & 7;
    const int vg = tid >> 3;
    int vs[4]; bool vok[4];
#pragma unroll
    for (int s = 0; s < 4; s++) {
        int v = v0 + vg + 32 * s;
        vok[s] = (v < NVERT);
        vs[s] = vok[s] ? v : (NVERT - 1);
    }

    // read v_posed (all reads before this thread's own writes; thread owns its 8 cells)
    float a[2][4][3];
#pragma unroll
    for (int i = 0; i < 2; i++)
#pragma unroll
        for (int s = 0; s < 4; s++) {
            const float* ap = out + ((size_t)(b0 + bg * 2 + i) * NVERT + vs[s]) * 3;
            a[i][s][0] = ap[0]; a[i][s][1] = ap[1]; a[i][s][2] = ap[2];
        }

#pragma unroll
    for (int i = 0; i < 2; i++) {
        const int bl = bg * 2 + i;
        const float* gb = &sG3[bl * 292];
        float T[4][12];
#pragma unroll
        for (int s = 0; s < 4; s++)
#pragma unroll
            for (int c = 0; c < 12; c++) T[s][c] = 0.0f;
        for (int j = 0; j < 24; j++) {
            float4 g0 = *(const float4*)(gb + j * 12);
            float4 g1 = *(const float4*)(gb + j * 12 + 4);
            float4 g2 = *(const float4*)(gb + j * 12 + 8);
            const float* wrow = wT + j * 6912;
#pragma unroll
            for (int s = 0; s < 4; s++) {
                float wv = wrow[vs[s]];
                T[s][0] += wv * g0.x; T[s][1] += wv * g0.y;
                T[s][2] += wv * g0.z; T[s][3] += wv * g0.w;
                T[s][4] += wv * g1.x; T[s][5] += wv * g1.y;
                T[s][6] += wv * g1.z; T[s][7] += wv * g1.w;
                T[s][8] += wv * g2.x; T[s][9] += wv * g2.y;
                T[s][10] += wv * g2.z; T[s][11] += wv * g2.w;
            }
        }
#pragma unroll
        for (int s = 0; s < 4; s++) {
            float x = a[i][s][0], y = a[i][s][1], z = a[i][s][2];
            float o0 = T[s][0] * x + T[s][1] * y + T[s][2] * z + T[s][3];
            float o1 = T[s][4] * x + T[s][5] * y + T[s][6] * z + T[s][7];
            float o2 = T[s][8] * x + T[s][9] * y + T[s][10] * z + T[s][11];
            if (vok[s]) {
                float* op = out + ((size_t)(b0 + bl) * NVERT + (v0 + vg + 32 * s)) * 3;
                op[0] = o0; op[1] = o1; op[2] = o2;
            }
        }
    }
}

extern "C" void kernel_launch(void* const* d_in, const int* in_sizes, int n_in,
                              void* d_out, int out_size, void* d_ws, size_t ws_size,
                              hipStream_t stream) {
    const float* pose = (const float*)d_in[0];
    const float* beta = (const float*)d_in[1];
    const float* vtm  = (const float*)d_in[2];
    const float* sh   = (const float*)d_in[3];
    const float* pd   = (const float*)d_in[4];
    const float* Jr   = (const float*)d_in[5];
    const float* wts  = (const float*)d_in[6];
    float* out = (float*)d_out;

    __hip_bfloat16* Bt = (__hip_bfloat16*)d_ws;                  // 4,644,864 bf16
    __hip_bfloat16* A  = Bt + (size_t)NPAD * KDIM;               //   114,688 bf16
    float* g3 = (float*)(A + NBATCH * KDIM);                     //   147,456 f
    float* jb = g3 + NBATCH * 288;                               //       792 f
    float* wT = jb + 792;                                        //   165,888 f

    k_prep<<<2048, 256, 0, stream>>>(pd, sh, wts, Bt, wT);
    k_jreg<<<72, 256, 0, stream>>>(Jr, vtm, sh, jb);
    k_pose<<<NBATCH, 128, 0, stream>>>(pose, beta, jb, A, g3);
    k_gemm<<<dim3(81, 16), 256, 0, stream>>>(A, Bt, vtm, out);
    k_lbs<<<dim3(32, 54), 256, 0, stream>>>(g3, wT, out);
}

// Round 14
// 191.108 us; speedup vs baseline: 1.5631x; 1.0423x over previous
//
#include <hip/hip_runtime.h>
#include <hip/hip_bf16.h>
#include <math.h>

#define NVERT 6890
#define NJN   24
#define NBETA 10
#define NPOSE 207
#define NBATCH 512
#define KDIM  224          // 207 lrotmin + 10 beta + 7 zero pad
#define NCOL  20670        // NVERT*3
#define NPAD  20736        // 81*256 (GEMM N padding)
#define VPAD  6912         // vertex pad for Wb

typedef __attribute__((ext_vector_type(8))) short bh8;   // 8 bf16 in 4 VGPRs
typedef __attribute__((ext_vector_type(4))) float f4;

__device__ const int c_parent[23] = {0,0,0,1,2,3,4,5,6,7,8,9,9,9,12,13,14,16,17,18,19,20,21};

// ws layout (bf16 region first, then f32):
//  Bt : bf16 [NPAD][KDIM]   = 4,644,864
//  A  : bf16 [NBATCH][KDIM] =   114,688
//  Gb : bf16 [NBATCH][16][32] = 262,144   (A-frag layout: row=comp, k=joint)
//  Wb : bf16 [VPAD][32]     =   221,184   (B-frag layout: col=vert, k=joint)
//  jb : f32  792
//  total ~10.5 MB

// ---------- kernel 0: repack B^T (bf16) + weights -> Wb bf16 [v][32] ----------
__global__ void k_prep(const float* __restrict__ pd, const float* __restrict__ sh,
                       const float* __restrict__ wts,
                       __hip_bfloat16* __restrict__ Bt, __hip_bfloat16* __restrict__ Wb) {
    const int btTotal = NPAD * KDIM;          // 4,644,864
    const int wbTotal = VPAD * 32;            //   221,184
    const int total = btTotal + wbTotal;
    for (int idx = blockIdx.x * blockDim.x + threadIdx.x; idx < total;
         idx += gridDim.x * blockDim.x) {
        if (idx < btTotal) {
            int col = idx / KDIM;
            int k = idx - col * KDIM;
            float val = 0.0f;
            if (col < NCOL) {
                int v = col / 3, d = col - v * 3;
                if (k < NPOSE)      val = pd[v * 621 + d * 207 + k];
                else if (k < 217)   val = sh[v * 30 + d * 10 + (k - 207)];
            }
            Bt[idx] = __float2bfloat16(val);
        } else {
            int r = idx - btTotal;
            int v = r >> 5, j = r & 31;
            float val = (v < NVERT && j < NJN) ? wts[v * NJN + j] : 0.0f;
            Wb[r] = __float2bfloat16(val);
        }
    }
}

// ---------- kernel 1: fold J_regressor through template+shapedirs ----------
__global__ void k_jreg(const float* __restrict__ Jr, const float* __restrict__ vt,
                       const float* __restrict__ sh, float* __restrict__ jb) {
    const int jd = blockIdx.x;         // 0..71
    const int j = jd / 3, d = jd % 3;
    float acc[11];
#pragma unroll
    for (int k = 0; k < 11; k++) acc[k] = 0.0f;
    for (int v = threadIdx.x; v < NVERT; v += 256) {
        float r = Jr[j * NVERT + v];
        acc[0] += r * vt[v * 3 + d];
        const float* sp = sh + v * 30 + d * 10;
#pragma unroll
        for (int k = 0; k < 10; k++) acc[1 + k] += r * sp[k];
    }
#pragma unroll
    for (int k = 0; k < 11; k++) {
#pragma unroll
        for (int off = 32; off > 0; off >>= 1)
            acc[k] += __shfl_down(acc[k], off);
    }
    __shared__ float red[4][11];
    const int lane = threadIdx.x & 63, wid = threadIdx.x >> 6;
    if (lane == 0) {
#pragma unroll
        for (int k = 0; k < 11; k++) red[wid][k] = acc[k];
    }
    __syncthreads();
    if (threadIdx.x == 0) {
#pragma unroll
        for (int k = 0; k < 11; k++) {
            float s = red[0][k] + red[1][k] + red[2][k] + red[3][k];
            if (k == 0) jb[jd] = s;
            else jb[72 + jd * 10 + (k - 1)] = s;
        }
    }
}

// ---------- kernel 2: rodrigues + chain -> A row (bf16) + Gb bf16 A-frags ----------
// blockDim must be >= 72.
__global__ void k_pose(const float* __restrict__ pose, const float* __restrict__ beta,
                       const float* __restrict__ jb, __hip_bfloat16* __restrict__ A,
                       __hip_bfloat16* __restrict__ Gb) {
    const int b = blockIdx.x, t = threadIdx.x;
    __shared__ float sR[24][9], sJ[24][3], sGl[24][12], sG[24][12], sT[12][32];
    if (t < 24) {
        const float* th = pose + b * 72 + t * 3;
        float tx = th[0], ty = th[1], tz = th[2];
        float ax = tx + 1e-8f, ay = ty + 1e-8f, az = tz + 1e-8f;
        float ang = sqrtf(ax * ax + ay * ay + az * az);
        float inv = 1.0f / ang;
        float nx = tx * inv, ny = ty * inv, nz = tz * inv;
        float sw, cw;
        sincosf(0.5f * ang, &sw, &cw);
        float qw = cw, qx = sw * nx, qy = sw * ny, qz = sw * nz;
        float qn = 1.0f / sqrtf(qw * qw + qx * qx + qy * qy + qz * qz);
        qw *= qn; qx *= qn; qy *= qn; qz *= qn;
        float w2 = qw * qw, x2 = qx * qx, y2 = qy * qy, z2 = qz * qz;
        float wx = qw * qx, wy = qw * qy, wz = qw * qz;
        float xy = qx * qy, xz = qx * qz, yz = qy * qz;
        float R[9];
        R[0] = w2 + x2 - y2 - z2; R[1] = 2.f * (xy - wz); R[2] = 2.f * (wy + xz);
        R[3] = 2.f * (wz + xy);   R[4] = w2 - x2 + y2 - z2; R[5] = 2.f * (yz - wx);
        R[6] = 2.f * (xz - wy);   R[7] = 2.f * (wx + yz);   R[8] = w2 - x2 - y2 + z2;
#pragma unroll
        for (int k = 0; k < 9; k++) sR[t][k] = R[k];
        if (t >= 1) {
            __hip_bfloat16* ap = A + b * KDIM + (t - 1) * 9;
#pragma unroll
            for (int k = 0; k < 9; k++)
                ap[k] = __float2bfloat16(R[k] - ((k == 0 || k == 4 || k == 8) ? 1.f : 0.f));
        }
    }
    if (t < NBETA) A[b * KDIM + 207 + t] = __float2bfloat16(beta[b * NBETA + t]);
    if (t < 7)     A[b * KDIM + 217 + t] = __float2bfloat16(0.0f);
    if (t < 72) {
        const int j = t / 3;
        float Jv = jb[t];
        const float* c = jb + 72 + t * 10;
        const float* be = beta + b * NBETA;
#pragma unroll
        for (int k = 0; k < 10; k++) Jv += c[k] * be[k];
        sJ[j][t - j * 3] = Jv;
    }
    __syncthreads();
    if (t < 24) {
#pragma unroll
        for (int r = 0; r < 3; r++) {
            sGl[t][r * 4 + 0] = sR[t][r * 3 + 0];
            sGl[t][r * 4 + 1] = sR[t][r * 3 + 1];
            sGl[t][r * 4 + 2] = sR[t][r * 3 + 2];
            float jr = sJ[t][r];
            if (t > 0) jr -= sJ[c_parent[t - 1]][r];
            sGl[t][r * 4 + 3] = jr;
        }
    }
    __syncthreads();
    if (t < 12) sG[0][t] = sGl[0][t];
    __syncthreads();
    for (int i = 1; i < 24; i++) {
        if (t < 12) {
            const int m = t >> 2, n = t & 3;
            const int p = c_parent[i - 1];
            float val = sG[p][m * 4 + 0] * sGl[i][0 + n]
                      + sG[p][m * 4 + 1] * sGl[i][4 + n]
                      + sG[p][m * 4 + 2] * sGl[i][8 + n];
            if (n == 3) val += sG[p][m * 4 + 3];
            sG[i][t] = val;
        }
        __syncthreads();
    }
    // fold t_corr and transpose to [comp][joint] for the MFMA A-fragment
    if (t < 24) {
        float jx = sJ[t][0], jy = sJ[t][1], jz = sJ[t][2];
#pragma unroll
        for (int m = 0; m < 3; m++) {
            float g0 = sG[t][m * 4 + 0], g1 = sG[t][m * 4 + 1];
            float g2 = sG[t][m * 4 + 2], g3v = sG[t][m * 4 + 3];
            float tc = g0 * jx + g1 * jy + g2 * jz;
            sT[m * 4 + 0][t] = g0; sT[m * 4 + 1][t] = g1;
            sT[m * 4 + 2][t] = g2; sT[m * 4 + 3][t] = g3v - tc;
        }
    }
    __syncthreads();
    if (t < 16) {
        __hip_bfloat16* gbp = Gb + b * 512 + t * 32;
#pragma unroll
        for (int j = 0; j < 32; j++) {
            float v = (t < 12 && j < 24) ? sT[t][j] : 0.0f;
            gbp[j] = __float2bfloat16(v);
        }
    }
}

// ---------- kernel 3: MFMA GEMM  v_posed = A[512,224] x B[224,20670] + v_template ----------
__global__ __launch_bounds__(256) void k_gemm(const __hip_bfloat16* __restrict__ A,
                                              const __hip_bfloat16* __restrict__ Bt,
                                              const float* __restrict__ vt,
                                              float* __restrict__ out) {
    const int lane = threadIdx.x & 63;
    const int wv = threadIdx.x >> 6;
    const int m0 = blockIdx.y * 32;
    const int n0 = blockIdx.x * 256 + wv * 64;
    const int l15 = lane & 15, lg = lane >> 4;

    const short* Ap = (const short*)A + (m0 + l15) * KDIM + lg * 8;
    const short* Bp = (const short*)Bt + (size_t)(n0 + l15) * KDIM + lg * 8;

    f4 acc[2][4];
#pragma unroll
    for (int mt = 0; mt < 2; mt++)
#pragma unroll
        for (int nr = 0; nr < 4; nr++) acc[mt][nr] = (f4){0.f, 0.f, 0.f, 0.f};

#pragma unroll
    for (int kk = 0; kk < 7; kk++) {
        bh8 a0 = *(const bh8*)(Ap + kk * 32);
        bh8 a1 = *(const bh8*)(Ap + 16 * KDIM + kk * 32);
#pragma unroll
        for (int nr = 0; nr < 4; nr++) {
            bh8 b = *(const bh8*)(Bp + (size_t)nr * 16 * KDIM + kk * 32);
            acc[0][nr] = __builtin_amdgcn_mfma_f32_16x16x32_bf16(a0, b, acc[0][nr], 0, 0, 0);
            acc[1][nr] = __builtin_amdgcn_mfma_f32_16x16x32_bf16(a1, b, acc[1][nr], 0, 0, 0);
        }
    }

#pragma unroll
    for (int mt = 0; mt < 2; mt++) {
#pragma unroll
        for (int nr = 0; nr < 4; nr++) {
            int col = n0 + nr * 16 + l15;
            if (col < NCOL) {
                float tv = vt[col];
                int rowb = m0 + mt * 16 + lg * 4;
#pragma unroll
                for (int r = 0; r < 4; r++)
                    out[(size_t)(rowb + r) * NCOL + col] = acc[mt][nr][r] + tv;
            }
        }
    }
}

// ---------- kernel 4: LBS via MFMA, in-place on d_out ----------
// T[b, comp, v] = sum_j Gb[b][comp][j] * Wb[v][j]  (one 16x16x32 MFMA per b per 16 verts)
// C layout: col = lane&15 = vert, rows = (lane>>4)*4 + r = comps; lane group lg<3 owns out dim lg.
__global__ __launch_bounds__(256) void k_lbs(const __hip_bfloat16* __restrict__ Gb,
                                             const __hip_bfloat16* __restrict__ Wb,
                                             float* __restrict__ out) {
    const int w = threadIdx.x >> 6, lane = threadIdx.x & 63;
    const int l15 = lane & 15, lg = lane >> 4;
    const int v = blockIdx.x * 64 + w * 16 + l15;      // this lane's vertex (col)
    const int b0 = blockIdx.y * 64;
    const bool vreal = (v < NVERT);
    const int vc = vreal ? v : (NVERT - 1);            // clamp for loads only
    const bool doio = (lg < 3);

    bh8 wf = *(const bh8*)((const short*)Wb + v * 32 + lg * 8);   // v < VPAD always

    for (int b = b0; b < b0 + 64; b++) {
        bh8 gf = *(const bh8*)((const short*)Gb + b * 512 + l15 * 32 + lg * 8);
        f4 T = __builtin_amdgcn_mfma_f32_16x16x32_bf16(gf, wf, (f4){0.f, 0.f, 0.f, 0.f}, 0, 0, 0);
        float x = 0.f, y = 0.f, z = 0.f;
        if (doio) {
            const float* ap = out + ((size_t)b * NVERT + vc) * 3;
            x = ap[0]; y = ap[1]; z = ap[2];
        }
        float val = T[0] * x + T[1] * y + T[2] * z + T[3];
        if (doio && vreal)
            out[((size_t)b * NVERT + v) * 3 + lg] = val;
    }
}

extern "C" void kernel_launch(void* const* d_in, const int* in_sizes, int n_in,
                              void* d_out, int out_size, void* d_ws, size_t ws_size,
                              hipStream_t stream) {
    const float* pose = (const float*)d_in[0];
    const float* beta = (const float*)d_in[1];
    const float* vtm  = (const float*)d_in[2];
    const float* sh   = (const float*)d_in[3];
    const float* pd   = (const float*)d_in[4];
    const float* Jr   = (const float*)d_in[5];
    const float* wts  = (const float*)d_in[6];
    float* out = (float*)d_out;

    __hip_bfloat16* Bt = (__hip_bfloat16*)d_ws;                  // 4,644,864 bf16
    __hip_bfloat16* A  = Bt + (size_t)NPAD * KDIM;               //   114,688 bf16
    __hip_bfloat16* Gb = A + NBATCH * KDIM;                      //   262,144 bf16
    __hip_bfloat16* Wb = Gb + NBATCH * 512;                      //   221,184 bf16
    float* jb = (float*)(Wb + VPAD * 32);                        //       792 f32

    k_prep<<<2048, 256, 0, stream>>>(pd, sh, wts, Bt, Wb);
    k_jreg<<<72, 256, 0, stream>>>(Jr, vtm, sh, jb);
    k_pose<<<NBATCH, 128, 0, stream>>>(pose, beta, jb, A, Gb);
    k_gemm<<<dim3(81, 16), 256, 0, stream>>>(A, Bt, vtm, out);
    k_lbs<<<dim3(108, 8), 256, 0, stream>>>(Gb, Wb, out);
}

// Round 15
// 181.494 us; speedup vs baseline: 1.6459x; 1.0530x over previous
//
#include <hip/hip_runtime.h>
#include <hip/hip_bf16.h>
#include <math.h>

#define NVERT 6890
#define NJN   24
#define NBETA 10
#define NPOSE 207
#define NBATCH 512
#define KDIM  224          // 207 lrotmin + 10 beta + 7 zero pad
#define NCOL  20670        // NVERT*3
#define NPAD  20736        // 81*256 (GEMM N padding)
#define VPAD  6912         // vertex pad for Wb

typedef __attribute__((ext_vector_type(8))) short bh8;   // 8 bf16 in 4 VGPRs
typedef __attribute__((ext_vector_type(4))) float f4;

__device__ const int c_parent[23] = {0,0,0,1,2,3,4,5,6,7,8,9,9,9,12,13,14,16,17,18,19,20,21};

// ws layout (bf16 region first, then f32):
//  Bt : bf16 [NPAD][KDIM]     = 4,644,864
//  A  : bf16 [NBATCH][KDIM]   =   114,688
//  Gb : bf16 [NBATCH][16][32] =   262,144
//  Wb : bf16 [VPAD][32]       =   221,184
//  jb : f32  792   (ZEROED via hipMemsetAsync; k_setup atomicAdds into it)

// ---------- kernel 0: merged prep (Bt,Wb repack) + J-regressor fold (8-way + atomics) ----------
// blocks [0,2048)   : grid-stride repack
// blocks [2048,2624): jd = (bid-2048)%72, chunk = (bid-2048)/72 -> partial sums -> atomicAdd jb
__global__ void k_setup(const float* __restrict__ pd, const float* __restrict__ sh,
                        const float* __restrict__ wts, const float* __restrict__ Jr,
                        const float* __restrict__ vt,
                        __hip_bfloat16* __restrict__ Bt, __hip_bfloat16* __restrict__ Wb,
                        float* __restrict__ jb) {
    __shared__ float red[4][11];
    if (blockIdx.x < 2048) {
        const int btTotal = NPAD * KDIM;
        const int total = btTotal + VPAD * 32;
        for (int idx = blockIdx.x * 256 + threadIdx.x; idx < total; idx += 2048 * 256) {
            if (idx < btTotal) {
                int col = idx / KDIM;
                int k = idx - col * KDIM;
                float val = 0.0f;
                if (col < NCOL) {
                    int v = col / 3, d = col - v * 3;
                    if (k < NPOSE)      val = pd[v * 621 + d * 207 + k];
                    else if (k < 217)   val = sh[v * 30 + d * 10 + (k - 207)];
                }
                Bt[idx] = __float2bfloat16(val);
            } else {
                int r = idx - btTotal;
                int v = r >> 5, j = r & 31;
                float val = (v < NVERT && j < NJN) ? wts[v * NJN + j] : 0.0f;
                Wb[r] = __float2bfloat16(val);
            }
        }
    } else {
        const int bid = blockIdx.x - 2048;     // 0..575
        const int jd = bid % 72, chunk = bid / 72;
        const int j = jd / 3, d = jd % 3;
        const int vstart = chunk * 862;
        int vend = vstart + 862; if (vend > NVERT) vend = NVERT;
        float acc[11];
#pragma unroll
        for (int k = 0; k < 11; k++) acc[k] = 0.0f;
        for (int v = vstart + threadIdx.x; v < vend; v += 256) {
            float r = Jr[j * NVERT + v];
            acc[0] += r * vt[v * 3 + d];
            const float* sp = sh + v * 30 + d * 10;
#pragma unroll
            for (int k = 0; k < 10; k++) acc[1 + k] += r * sp[k];
        }
#pragma unroll
        for (int k = 0; k < 11; k++) {
#pragma unroll
            for (int off = 32; off > 0; off >>= 1)
                acc[k] += __shfl_down(acc[k], off);
        }
        const int lane = threadIdx.x & 63, wid = threadIdx.x >> 6;
        if (lane == 0) {
#pragma unroll
            for (int k = 0; k < 11; k++) red[wid][k] = acc[k];
        }
        __syncthreads();
        if (threadIdx.x == 0) {
#pragma unroll
            for (int k = 0; k < 11; k++) {
                float s = red[0][k] + red[1][k] + red[2][k] + red[3][k];
                if (k == 0) atomicAdd(&jb[jd], s);
                else        atomicAdd(&jb[72 + jd * 10 + (k - 1)], s);
            }
        }
    }
}

// ---------- kernel 2: rodrigues + chain -> A row (bf16) + Gb bf16 A-frags ----------
// blockDim must be >= 72.
__global__ void k_pose(const float* __restrict__ pose, const float* __restrict__ beta,
                       const float* __restrict__ jb, __hip_bfloat16* __restrict__ A,
                       __hip_bfloat16* __restrict__ Gb) {
    const int b = blockIdx.x, t = threadIdx.x;
    __shared__ float sR[24][9], sJ[24][3], sGl[24][12], sG[24][12], sT[12][32];
    if (t < 24) {
        const float* th = pose + b * 72 + t * 3;
        float tx = th[0], ty = th[1], tz = th[2];
        float ax = tx + 1e-8f, ay = ty + 1e-8f, az = tz + 1e-8f;
        float ang = sqrtf(ax * ax + ay * ay + az * az);
        float inv = 1.0f / ang;
        float nx = tx * inv, ny = ty * inv, nz = tz * inv;
        float sw, cw;
        sincosf(0.5f * ang, &sw, &cw);
        float qw = cw, qx = sw * nx, qy = sw * ny, qz = sw * nz;
        float qn = 1.0f / sqrtf(qw * qw + qx * qx + qy * qy + qz * qz);
        qw *= qn; qx *= qn; qy *= qn; qz *= qn;
        float w2 = qw * qw, x2 = qx * qx, y2 = qy * qy, z2 = qz * qz;
        float wx = qw * qx, wy = qw * qy, wz = qw * qz;
        float xy = qx * qy, xz = qx * qz, yz = qy * qz;
        float R[9];
        R[0] = w2 + x2 - y2 - z2; R[1] = 2.f * (xy - wz); R[2] = 2.f * (wy + xz);
        R[3] = 2.f * (wz + xy);   R[4] = w2 - x2 + y2 - z2; R[5] = 2.f * (yz - wx);
        R[6] = 2.f * (xz - wy);   R[7] = 2.f * (wx + yz);   R[8] = w2 - x2 - y2 + z2;
#pragma unroll
        for (int k = 0; k < 9; k++) sR[t][k] = R[k];
        if (t >= 1) {
            __hip_bfloat16* ap = A + b * KDIM + (t - 1) * 9;
#pragma unroll
            for (int k = 0; k < 9; k++)
                ap[k] = __float2bfloat16(R[k] - ((k == 0 || k == 4 || k == 8) ? 1.f : 0.f));
        }
    }
    if (t < NBETA) A[b * KDIM + 207 + t] = __float2bfloat16(beta[b * NBETA + t]);
    if (t < 7)     A[b * KDIM + 217 + t] = __float2bfloat16(0.0f);
    if (t < 72) {
        const int j = t / 3;
        float Jv = jb[t];
        const float* c = jb + 72 + t * 10;
        const float* be = beta + b * NBETA;
#pragma unroll
        for (int k = 0; k < 10; k++) Jv += c[k] * be[k];
        sJ[j][t - j * 3] = Jv;
    }
    __syncthreads();
    if (t < 24) {
#pragma unroll
        for (int r = 0; r < 3; r++) {
            sGl[t][r * 4 + 0] = sR[t][r * 3 + 0];
            sGl[t][r * 4 + 1] = sR[t][r * 3 + 1];
            sGl[t][r * 4 + 2] = sR[t][r * 3 + 2];
            float jr = sJ[t][r];
            if (t > 0) jr -= sJ[c_parent[t - 1]][r];
            sGl[t][r * 4 + 3] = jr;
        }
    }
    __syncthreads();
    if (t < 12) sG[0][t] = sGl[0][t];
    __syncthreads();
    for (int i = 1; i < 24; i++) {
        if (t < 12) {
            const int m = t >> 2, n = t & 3;
            const int p = c_parent[i - 1];
            float val = sG[p][m * 4 + 0] * sGl[i][0 + n]
                      + sG[p][m * 4 + 1] * sGl[i][4 + n]
                      + sG[p][m * 4 + 2] * sGl[i][8 + n];
            if (n == 3) val += sG[p][m * 4 + 3];
            sG[i][t] = val;
        }
        __syncthreads();
    }
    // fold t_corr and transpose to [comp][joint] for the MFMA A-fragment
    if (t < 24) {
        float jx = sJ[t][0], jy = sJ[t][1], jz = sJ[t][2];
#pragma unroll
        for (int m = 0; m < 3; m++) {
            float g0 = sG[t][m * 4 + 0], g1 = sG[t][m * 4 + 1];
            float g2 = sG[t][m * 4 + 2], g3v = sG[t][m * 4 + 3];
            float tc = g0 * jx + g1 * jy + g2 * jz;
            sT[m * 4 + 0][t] = g0; sT[m * 4 + 1][t] = g1;
            sT[m * 4 + 2][t] = g2; sT[m * 4 + 3][t] = g3v - tc;
        }
    }
    __syncthreads();
    if (t < 16) {
        __hip_bfloat16* gbp = Gb + b * 512 + t * 32;
#pragma unroll
        for (int j = 0; j < 32; j++) {
            float v = (t < 12 && j < 24) ? sT[t][j] : 0.0f;
            gbp[j] = __float2bfloat16(v);
        }
    }
}

// ---------- kernel 3: MFMA GEMM, 8 m-tiles/wave (128m x 64n per wave, 128x256 per block) ----------
// B-frag reused 8x; grid (81, 4).
__global__ __launch_bounds__(256) void k_gemm(const __hip_bfloat16* __restrict__ A,
                                              const __hip_bfloat16* __restrict__ Bt,
                                              const float* __restrict__ vt,
                                              float* __restrict__ out) {
    const int lane = threadIdx.x & 63;
    const int wv = threadIdx.x >> 6;
    const int m0 = blockIdx.y * 128;
    const int n0 = blockIdx.x * 256 + wv * 64;
    const int l15 = lane & 15, lg = lane >> 4;

    const short* Ap = (const short*)A + (m0 + l15) * KDIM + lg * 8;
    const short* Bp = (const short*)Bt + (size_t)(n0 + l15) * KDIM + lg * 8;

    f4 acc[8][4];
#pragma unroll
    for (int mt = 0; mt < 8; mt++)
#pragma unroll
        for (int nr = 0; nr < 4; nr++) acc[mt][nr] = (f4){0.f, 0.f, 0.f, 0.f};

#pragma unroll
    for (int kk = 0; kk < 7; kk++) {
        bh8 a[8];
#pragma unroll
        for (int mt = 0; mt < 8; mt++)
            a[mt] = *(const bh8*)(Ap + mt * 16 * KDIM + kk * 32);
#pragma unroll
        for (int nr = 0; nr < 4; nr++) {
            bh8 b = *(const bh8*)(Bp + (size_t)nr * 16 * KDIM + kk * 32);
#pragma unroll
            for (int mt = 0; mt < 8; mt++)
                acc[mt][nr] = __builtin_amdgcn_mfma_f32_16x16x32_bf16(a[mt], b, acc[mt][nr], 0, 0, 0);
        }
    }

#pragma unroll
    for (int nr = 0; nr < 4; nr++) {
        int col = n0 + nr * 16 + l15;
        if (col < NCOL) {
            float tv = vt[col];
#pragma unroll
            for (int mt = 0; mt < 8; mt++) {
                int rowb = m0 + mt * 16 + lg * 4;
#pragma unroll
                for (int r = 0; r < 4; r++)
                    out[(size_t)(rowb + r) * NCOL + col] = acc[mt][nr][r] + tv;
            }
        }
    }
}

// ---------- kernel 4: LBS via MFMA, in-place on d_out ----------
__global__ __launch_bounds__(256) void k_lbs(const __hip_bfloat16* __restrict__ Gb,
                                             const __hip_bfloat16* __restrict__ Wb,
                                             float* __restrict__ out) {
    const int w = threadIdx.x >> 6, lane = threadIdx.x & 63;
    const int l15 = lane & 15, lg = lane >> 4;
    const int v = blockIdx.x * 64 + w * 16 + l15;
    const int b0 = blockIdx.y * 64;
    const bool vreal = (v < NVERT);
    const int vc = vreal ? v : (NVERT - 1);
    const bool doio = (lg < 3);

    bh8 wf = *(const bh8*)((const short*)Wb + v * 32 + lg * 8);

    for (int b = b0; b < b0 + 64; b++) {
        bh8 gf = *(const bh8*)((const short*)Gb + b * 512 + l15 * 32 + lg * 8);
        f4 T = __builtin_amdgcn_mfma_f32_16x16x32_bf16(gf, wf, (f4){0.f, 0.f, 0.f, 0.f}, 0, 0, 0);
        float x = 0.f, y = 0.f, z = 0.f;
        if (doio) {
            const float* ap = out + ((size_t)b * NVERT + vc) * 3;
            x = ap[0]; y = ap[1]; z = ap[2];
        }
        float val = T[0] * x + T[1] * y + T[2] * z + T[3];
        if (doio && vreal)
            out[((size_t)b * NVERT + v) * 3 + lg] = val;
    }
}

extern "C" void kernel_launch(void* const* d_in, const int* in_sizes, int n_in,
                              void* d_out, int out_size, void* d_ws, size_t ws_size,
                              hipStream_t stream) {
    const float* pose = (const float*)d_in[0];
    const float* beta = (const float*)d_in[1];
    const float* vtm  = (const float*)d_in[2];
    const float* sh   = (const float*)d_in[3];
    const float* pd   = (const float*)d_in[4];
    const float* Jr   = (const float*)d_in[5];
    const float* wts  = (const float*)d_in[6];
    float* out = (float*)d_out;

    __hip_bfloat16* Bt = (__hip_bfloat16*)d_ws;                  // 4,644,864 bf16
    __hip_bfloat16* A  = Bt + (size_t)NPAD * KDIM;               //   114,688 bf16
    __hip_bfloat16* Gb = A + NBATCH * KDIM;                      //   262,144 bf16
    __hip_bfloat16* Wb = Gb + NBATCH * 512;                      //   221,184 bf16
    float* jb = (float*)(Wb + VPAD * 32);                        //       792 f32

    hipMemsetAsync(jb, 0, 792 * sizeof(float), stream);
    k_setup<<<2624, 256, 0, stream>>>(pd, sh, wts, Jr, vtm, Bt, Wb, jb);
    k_pose<<<NBATCH, 128, 0, stream>>>(pose, beta, jb, A, Gb);
    k_gemm<<<dim3(81, 4), 256, 0, stream>>>(A, Bt, vtm, out);
    k_lbs<<<dim3(108, 8), 256, 0, stream>>>(Gb, Wb, out);
}